// Round 3
// baseline (226.788 us; speedup 1.0000x reference)
//
#include <hip/hip_runtime.h>

// ContrastiveLoss: loss = sum_n [ log(sum_j exp(2*<ne_n,ne_j>)) - 2*<ne_n,nt_n> ] / (2N)
// N=8192, D=512.
// R15 = R14 minus register pressure. R13/R14 post-mortem: both mfma_scale
// variants (LDS-staged and barrier-free) showed the SAME signature -- WRITE
// ~229 MB/iter (logical writes: 4 MB), FETCH ~135 MB, VGPR_Count clamped at
// 84, MfmaUtil 7% -- i.e. SCRATCH SPILL: the depth-1 prefetch structure needs
// ~150 regs (64 acc + 32 cur + 32 prefetch + 16 fa/fb + addr), allocator
// clamped to 84 and spilled ~430 B/thread/iter to scratch at HBM latency.
// Fix: delete the explicit prefetch arrays. Each window loads its 8 dwordx4
// directly into fa/fb before use (~112 regs peak). __launch_bounds__(256,4)
// -> 4 blocks/CU = 16 waves/CU; wave-level TLP (m114 overlap) hides the
// per-window L2 latency; the unrolled 8-window loop lets the compiler
// pipeline ahead to whatever depth the 128-reg budget allows.
//   k_norm : fused normalize + fp8 e4m3 convert storing the MX layout
//            (verified absmax 0.0 in R13/R14): 32-row blocks (16 KB), 8
//            windows of 64 k (2 KB = lo-16B half 1 KB | hi-16B half 1 KB);
//            gemm lane l = g*32+m reads its 32 B k-slice as two dwordx4 at
//            block*16384 + w*2048 + {0,1024} + lane*16.
//   k_gemm : barrier-free K-loop, no explicit prefetch, 2x2 waves x 2x2
//            tiles of mfma_scale_f32_32x32x64_f8f6f4 (unit E8M0 scales),
//            symmetric triangle (row-sums + col-sums), XCD-partitioned
//            schedule, 32x32 C/D epilogue (col=lane&31,
//            row=(r&3)+8*(r>>2)+4*(lane>>5)), fp32 exp/sum.
//   k_final: unchanged.

typedef __attribute__((ext_vector_type(16))) float floatx16;
typedef __attribute__((ext_vector_type(4)))  int   intx4;
typedef __attribute__((ext_vector_type(8)))  int   intx8;
typedef unsigned int u32;

#define N 8192
#define D 512
#define NT 64            // 128-row tiles per dim

// Per-XCD segment tables: 5 segments each = [diag36, off64, off64, off64, half32].
__device__ __constant__ unsigned char seg_ga[8][5] = {
    {0,0,0,0,0},{1,1,1,1,0},{2,2,2,2,2},{3,3,3,3,2},
    {4,0,0,0,4},{5,1,1,1,4},{6,2,3,4,6},{7,4,5,5,6}};
__device__ __constant__ unsigned char seg_gb[8][5] = {
    {0,2,3,4,1},{1,2,3,4,1},{2,5,6,7,3},{3,5,6,7,3},
    {4,5,6,7,5},{5,5,6,7,5},{6,4,4,6,7},{7,7,6,7,7}};

__global__ __launch_bounds__(256) void k_norm(const float* __restrict__ emb,
                                              const float* __restrict__ tgt,
                                              unsigned char* __restrict__ neb,
                                              float* __restrict__ pos,
                                              float* __restrict__ out) {
    if (blockIdx.x == 0 && threadIdx.x == 0) *out = 0.0f;   // replaces memset dispatch
    int wave = threadIdx.x >> 6;
    int lane = threadIdx.x & 63;
    int row  = blockIdx.x * 4 + wave;          // one wave per row; lane holds k=lane*8..+8
    const float4* e4 = (const float4*)(emb + (size_t)row * D) + lane * 2;
    const float4* t4 = (const float4*)(tgt + (size_t)row * D) + lane * 2;
    float4 e0 = e4[0], e1 = e4[1];
    float4 t0 = t4[0], t1 = t4[1];
    float ee = e0.x*e0.x + e0.y*e0.y + e0.z*e0.z + e0.w*e0.w
             + e1.x*e1.x + e1.y*e1.y + e1.z*e1.z + e1.w*e1.w;
    float tt = t0.x*t0.x + t0.y*t0.y + t0.z*t0.z + t0.w*t0.w
             + t1.x*t1.x + t1.y*t1.y + t1.z*t1.z + t1.w*t1.w;
    float et = e0.x*t0.x + e0.y*t0.y + e0.z*t0.z + e0.w*t0.w
             + e1.x*t1.x + e1.y*t1.y + e1.z*t1.z + e1.w*t1.w;
    #pragma unroll
    for (int off = 1; off < 64; off <<= 1) {
        ee += __shfl_xor(ee, off);
        tt += __shfl_xor(tt, off);
        et += __shfl_xor(et, off);
    }
    float se = fmaxf(sqrtf(ee), 1e-12f);
    float st = fmaxf(sqrtf(tt), 1e-12f);
    if (lane == 0) pos[row] = et / (se * st);
    float inv = 1.0f / se;
    // pack 8 e4m3 bytes (k ascending) via HW RNE converts
    int w0 = __builtin_amdgcn_cvt_pk_fp8_f32(e0.x * inv, e0.y * inv, 0, false);
    w0     = __builtin_amdgcn_cvt_pk_fp8_f32(e0.z * inv, e0.w * inv, w0, true);
    int w1 = __builtin_amdgcn_cvt_pk_fp8_f32(e1.x * inv, e1.y * inv, 0, false);
    w1     = __builtin_amdgcn_cvt_pk_fp8_f32(e1.z * inv, e1.w * inv, w1, true);
    uint2 pk; pk.x = (unsigned)w0; pk.y = (unsigned)w1;
    // MX-layout shuffled store (verified R13/R14). Row r, byte kb = lane*8:
    //   block b32 = r>>5 (16 KB), window w = kb>>6 (2 KB), khalf g = (kb>>5)&1,
    //   16B-half h = (kb>>4)&1, uint2 parity = lane&1.
    //   byte addr = b32*16384 + w*2048 + h*1024 + (g*32 + (r&31))*16 + (lane&1)*8
    size_t u2idx = (size_t)(row >> 5) * 2048
                 + (size_t)(lane >> 3) * 256
                 + (size_t)((lane >> 1) & 1) * 128
                 + (size_t)(((lane >> 2) & 1) * 32 + (row & 31)) * 2
                 + (lane & 1);
    ((uint2*)neb)[u2idx] = pk;
}

__global__ __launch_bounds__(256, 4) void k_gemm(const unsigned char* __restrict__ neb,
                                                 float* __restrict__ partial) {
    // XCD-partitioned decode: x = XCD stream, s = sequence within stream
    const int x = (int)(blockIdx.x & 7);
    int s = (int)(blockIdx.x >> 3);          // 0..259
    int seg, u;
    if (s < 36)       { seg = 0; u = s; }
    else if (s < 100) { seg = 1; u = s - 36; }
    else if (s < 164) { seg = 2; u = s - 100; }
    else if (s < 228) { seg = 3; u = s - 164; }
    else              { seg = 4; u = s - 228 + ((x & 1) ? 32 : 0); }
    const int ga = seg_ga[x][seg], gb = seg_gb[x][seg];
    int bi, bj;
    if (seg == 0) {                           // diag supertile: tri decode in 8x8
        int di = 0;
        while (u >= 8 - di) { u -= 8 - di; ++di; }
        bi = ga * 8 + di; bj = gb * 8 + di + u;
    } else {
        bi = ga * 8 + (u >> 3); bj = gb * 8 + (u & 7);
    }

    const int tid  = threadIdx.x;
    const int i0   = bi * 128, j0 = bj * 128;
    const int wave = tid >> 6, lane = tid & 63;
    const int wrow = wave >> 1, wcol = wave & 1;   // 2x2 waves, each 64x64

    // fragment bases: wave's A rows = two 32-row blocks (i0/32 + wrow*2 + t),
    // B cols = (j0/32 + wcol*2 + t). Lane's 32 B per fragment = two dwordx4 at
    // +0 / +1024 within the 2 KB window, lane offset lane*16 (contiguous 1 KB).
    const unsigned char* baseA = neb + (size_t)(i0 / 32 + wrow * 2) * 16384 + lane * 16;
    const unsigned char* baseB = neb + (size_t)(j0 / 32 + wcol * 2) * 16384 + lane * 16;

    floatx16 acc[2][2];
    #pragma unroll
    for (int a = 0; a < 2; ++a)
        #pragma unroll
        for (int b = 0; b < 2; ++b)
            #pragma unroll
            for (int e = 0; e < 16; ++e) acc[a][b][e] = 0.0f;

    #pragma unroll
    for (int w = 0; w < 8; ++w) {
        const size_t ko = (size_t)w * 2048;
        intx8 fa[2], fb[2];
        #pragma unroll
        for (int t = 0; t < 2; ++t) {
            intx4 alo = *(const intx4*)(baseA + (size_t)t * 16384 + ko);
            intx4 ahi = *(const intx4*)(baseA + (size_t)t * 16384 + ko + 1024);
            fa[t] = __builtin_shufflevector(alo, ahi, 0, 1, 2, 3, 4, 5, 6, 7);
            intx4 blo = *(const intx4*)(baseB + (size_t)t * 16384 + ko);
            intx4 bhi = *(const intx4*)(baseB + (size_t)t * 16384 + ko + 1024);
            fb[t] = __builtin_shufflevector(blo, bhi, 0, 1, 2, 3, 4, 5, 6, 7);
        }
        #pragma unroll
        for (int ti = 0; ti < 2; ++ti)
            #pragma unroll
            for (int tj = 0; tj < 2; ++tj)
                acc[ti][tj] = __builtin_amdgcn_mfma_scale_f32_32x32x64_f8f6f4(
                    fa[ti], fb[tj], acc[ti][tj],
                    0, 0,                // cbsz=FP8(e4m3), blgp=FP8(e4m3)
                    0, 0x7f7f7f7f,       // scale_a opsel, E8M0 = 127 -> 1.0
                    0, 0x7f7f7f7f);      // scale_b
    }

    // 32x32 C/D layout: col = lane&31, row = (r&3) + 8*(r>>2) + 4*(lane>>5)
    const int hi  = lane >> 5, l31 = lane & 31;

    // row-sums: exp(2*c) summed over this block's 128 cols -> slot bj*2+wcol
    const int prow = bj * 2 + wcol;
    const int R0   = i0 + wrow * 64;
    #pragma unroll
    for (int ti = 0; ti < 2; ++ti) {
        #pragma unroll
        for (int r = 0; r < 16; ++r) {
            float ss = __expf(2.0f * acc[ti][0][r]) + __expf(2.0f * acc[ti][1][r]);
            #pragma unroll
            for (int off = 1; off < 32; off <<= 1) ss += __shfl_xor(ss, off);
            if (l31 == 0) {
                int rowg = R0 + ti * 32 + (r & 3) + 8 * (r >> 2) + 4 * hi;
                partial[(size_t)prow * N + rowg] = ss;
            }
        }
    }
    // col-sums (symmetry: = row-sums of skipped tile (bj,bi)) -> slot bi*2+wrow
    if (bi < bj) {
        const int pcol = bi * 2 + wrow;
        const int C0   = j0 + wcol * 64;
        #pragma unroll
        for (int tj = 0; tj < 2; ++tj) {
            float css = 0.f;
            #pragma unroll
            for (int ti = 0; ti < 2; ++ti)
                #pragma unroll
                for (int r = 0; r < 16; ++r) css += __expf(2.0f * acc[ti][tj][r]);
            css += __shfl_xor(css, 32);
            if (hi == 0) partial[(size_t)pcol * N + (C0 + tj * 32 + l31)] = css;
        }
    }
}

__global__ __launch_bounds__(256) void k_final(const float* __restrict__ partial,
                                               const float* __restrict__ pos,
                                               float* __restrict__ out) {
    int tid = threadIdx.x;
    int row = blockIdx.x * 64 + (tid >> 2);
    int sub = tid & 3;
    float S = 0.f;
    #pragma unroll
    for (int i = 0; i < 32; ++i) S += partial[(size_t)(sub + i * 4) * N + row];
    S += __shfl_xor(S, 1);
    S += __shfl_xor(S, 2);
    float val = (sub == 0) ? (logf(S) - 2.0f * pos[row]) : 0.0f;
    #pragma unroll
    for (int off = 4; off < 64; off <<= 1) val += __shfl_xor(val, off);
    if ((tid & 63) == 0) atomicAdd(out, val * (1.0f / (2.0f * N)));
}

extern "C" void kernel_launch(void* const* d_in, const int* in_sizes, int n_in,
                              void* d_out, int out_size, void* d_ws, size_t ws_size,
                              hipStream_t stream) {
    const float* emb = (const float*)d_in[0];
    const float* tgt = (const float*)d_in[1];
    unsigned char* neb = (unsigned char*)d_ws;                                   // 4 MB fp8 ne (MX layout)
    float* pos     = (float*)((char*)d_ws + (size_t)N * D);                      // 32 KB
    float* partial = (float*)((char*)d_ws + (size_t)N * D + (size_t)N * 4);      // 4 MB
    float* out = (float*)d_out;

    k_norm<<<N / 4, 256, 0, stream>>>(emb, tgt, neb, pos, out);
    k_gemm<<<NT * (NT + 1) / 2, 256, 0, stream>>>(neb, partial);
    k_final<<<N / 64, 256, 0, stream>>>(partial, pos, out);
}

// Round 4
// 131.017 us; speedup vs baseline: 1.7310x; 1.7310x over previous
//
#include <hip/hip_runtime.h>

// ContrastiveLoss: loss = sum_n [ log(sum_j exp(2*<ne_n,ne_j>)) - 2*<ne_n,nt_n> ] / (2N)
// N=8192, D=512.
// R16: kill the spill. R13-R15 post-mortem (unified VGPR/AGPR arithmetic):
// acc floatx16[2][2] = 64 AGPRs hidden from VGPR_Count; reported count always
// landed at (launch-bounds cap - 64): (256,3)->84, (256,4)->64. Live set
// ~160-200 (acc + frags + shufflevector intx4->intx8 COPIES) >> cap => scratch
// spill; WRITE 229->336 MB and 98->145 us tracked the shrinking cap exactly.
// Fix:
//   1. __launch_bounds__(256,2): cap 256 unified regs. Live ~176 -> no spill.
//   2. MX layout v2: each gemm lane's 32 B k-slice is CONTIGUOUS
//      (window + lane*32), loaded as one intx8 (two adjacent dwordx4, no
//      shufflevector copies). Element->(row,k) map identical to the
//      R13/R14-verified one; only k_norm's store index changes.
//   3. Depth-2 prefetch, static 3-slot rotation (indices compile-time after
//      full unroll) -> ~2 windows (~270+ cyc) of load lead at 2 waves/SIMD.
//   k_gemm : barrier-free K-loop, 2x2 waves x 2x2 tiles of
//            mfma_scale_f32_32x32x64_f8f6f4 (unit E8M0 scales, 2.14x fp8
//            rate), symmetric triangle (row-sums + col-sums), XCD schedule,
//            32x32 C/D epilogue (col=lane&31, row=(r&3)+8*(r>>2)+4*(lane>>5)).
//   k_final: unchanged.

typedef __attribute__((ext_vector_type(16))) float floatx16;
typedef __attribute__((ext_vector_type(8)))  int   intx8;
typedef unsigned int u32;

#define N 8192
#define D 512
#define NT 64            // 128-row tiles per dim

// Per-XCD segment tables: 5 segments each = [diag36, off64, off64, off64, half32].
__device__ __constant__ unsigned char seg_ga[8][5] = {
    {0,0,0,0,0},{1,1,1,1,0},{2,2,2,2,2},{3,3,3,3,2},
    {4,0,0,0,4},{5,1,1,1,4},{6,2,3,4,6},{7,4,5,5,6}};
__device__ __constant__ unsigned char seg_gb[8][5] = {
    {0,2,3,4,1},{1,2,3,4,1},{2,5,6,7,3},{3,5,6,7,3},
    {4,5,6,7,5},{5,5,6,7,5},{6,4,4,6,7},{7,7,6,7,7}};

__global__ __launch_bounds__(256) void k_norm(const float* __restrict__ emb,
                                              const float* __restrict__ tgt,
                                              unsigned char* __restrict__ neb,
                                              float* __restrict__ pos,
                                              float* __restrict__ out) {
    if (blockIdx.x == 0 && threadIdx.x == 0) *out = 0.0f;   // replaces memset dispatch
    int wave = threadIdx.x >> 6;
    int lane = threadIdx.x & 63;
    int row  = blockIdx.x * 4 + wave;          // one wave per row; lane holds k=lane*8..+8
    const float4* e4 = (const float4*)(emb + (size_t)row * D) + lane * 2;
    const float4* t4 = (const float4*)(tgt + (size_t)row * D) + lane * 2;
    float4 e0 = e4[0], e1 = e4[1];
    float4 t0 = t4[0], t1 = t4[1];
    float ee = e0.x*e0.x + e0.y*e0.y + e0.z*e0.z + e0.w*e0.w
             + e1.x*e1.x + e1.y*e1.y + e1.z*e1.z + e1.w*e1.w;
    float tt = t0.x*t0.x + t0.y*t0.y + t0.z*t0.z + t0.w*t0.w
             + t1.x*t1.x + t1.y*t1.y + t1.z*t1.z + t1.w*t1.w;
    float et = e0.x*t0.x + e0.y*t0.y + e0.z*t0.z + e0.w*t0.w
             + e1.x*t1.x + e1.y*t1.y + e1.z*t1.z + e1.w*t1.w;
    #pragma unroll
    for (int off = 1; off < 64; off <<= 1) {
        ee += __shfl_xor(ee, off);
        tt += __shfl_xor(tt, off);
        et += __shfl_xor(et, off);
    }
    float se = fmaxf(sqrtf(ee), 1e-12f);
    float st = fmaxf(sqrtf(tt), 1e-12f);
    if (lane == 0) pos[row] = et / (se * st);
    float inv = 1.0f / se;
    // pack 8 e4m3 bytes (k ascending) via HW RNE converts
    int w0 = __builtin_amdgcn_cvt_pk_fp8_f32(e0.x * inv, e0.y * inv, 0, false);
    w0     = __builtin_amdgcn_cvt_pk_fp8_f32(e0.z * inv, e0.w * inv, w0, true);
    int w1 = __builtin_amdgcn_cvt_pk_fp8_f32(e1.x * inv, e1.y * inv, 0, false);
    w1     = __builtin_amdgcn_cvt_pk_fp8_f32(e1.z * inv, e1.w * inv, w1, true);
    uint2 pk; pk.x = (unsigned)w0; pk.y = (unsigned)w1;
    // MX layout v2 (contiguous 32 B per gemm lane). Row r, byte kb = lane*8:
    //   block b32 = r>>5 (16 KB), window w = kb>>6 (2 KB, 256 u2),
    //   khalf g = (kb>>5)&1  ->  gemm lane l = g*32 + (r&31), slot l*32 B,
    //   byte-in-slot = kb&31.
    //   u2idx = b32*2048 + w*256 + g*128 + (r&31)*4 + ((kb&31)>>3)
    size_t u2idx = (size_t)(row >> 5) * 2048
                 + (size_t)(lane >> 3) * 256
                 + (size_t)((lane >> 2) & 1) * 128
                 + (size_t)(row & 31) * 4
                 + (lane & 3);
    ((uint2*)neb)[u2idx] = pk;
}

__global__ __launch_bounds__(256, 2) void k_gemm(const unsigned char* __restrict__ neb,
                                                 float* __restrict__ partial) {
    // XCD-partitioned decode: x = XCD stream, s = sequence within stream
    const int x = (int)(blockIdx.x & 7);
    int s = (int)(blockIdx.x >> 3);          // 0..259
    int seg, u;
    if (s < 36)       { seg = 0; u = s; }
    else if (s < 100) { seg = 1; u = s - 36; }
    else if (s < 164) { seg = 2; u = s - 100; }
    else if (s < 228) { seg = 3; u = s - 164; }
    else              { seg = 4; u = s - 228 + ((x & 1) ? 32 : 0); }
    const int ga = seg_ga[x][seg], gb = seg_gb[x][seg];
    int bi, bj;
    if (seg == 0) {                           // diag supertile: tri decode in 8x8
        int di = 0;
        while (u >= 8 - di) { u -= 8 - di; ++di; }
        bi = ga * 8 + di; bj = gb * 8 + di + u;
    } else {
        bi = ga * 8 + (u >> 3); bj = gb * 8 + (u & 7);
    }

    const int tid  = threadIdx.x;
    const int i0   = bi * 128, j0 = bj * 128;
    const int wave = tid >> 6, lane = tid & 63;
    const int wrow = wave >> 1, wcol = wave & 1;   // 2x2 waves, each 64x64

    // fragment bases: wave's A rows = two 32-row blocks (i0/32 + wrow*2 + t),
    // B cols = (j0/32 + wcol*2 + t). Lane's 32 B k-slice is contiguous at
    // block*16384 + w*2048 + lane*32 -> one intx8 load (two adjacent dwordx4).
    const unsigned char* baseA = neb + (size_t)(i0 / 32 + wrow * 2) * 16384 + lane * 32;
    const unsigned char* baseB = neb + (size_t)(j0 / 32 + wcol * 2) * 16384 + lane * 32;

    floatx16 acc[2][2];
    #pragma unroll
    for (int a = 0; a < 2; ++a)
        #pragma unroll
        for (int b = 0; b < 2; ++b)
            #pragma unroll
            for (int e = 0; e < 16; ++e) acc[a][b][e] = 0.0f;

    // depth-2 software pipeline, 3-slot static rotation (full unroll ->
    // all slot indices compile-time; no runtime-indexed arrays, rule #20).
    intx8 fra[3][2], frb[3][2];
    #pragma unroll
    for (int w0_ = 0; w0_ < 2; ++w0_)
        #pragma unroll
        for (int t = 0; t < 2; ++t) {
            fra[w0_][t] = *(const intx8*)(baseA + (size_t)t * 16384 + (size_t)w0_ * 2048);
            frb[w0_][t] = *(const intx8*)(baseB + (size_t)t * 16384 + (size_t)w0_ * 2048);
        }

    #pragma unroll
    for (int w = 0; w < 8; ++w) {
        if (w + 2 < 8) {
            const int sl2 = (w + 2) % 3;
            const size_t ko = (size_t)(w + 2) * 2048;
            #pragma unroll
            for (int t = 0; t < 2; ++t) {
                fra[sl2][t] = *(const intx8*)(baseA + (size_t)t * 16384 + ko);
                frb[sl2][t] = *(const intx8*)(baseB + (size_t)t * 16384 + ko);
            }
        }
        const int sl = w % 3;
        #pragma unroll
        for (int ti = 0; ti < 2; ++ti)
            #pragma unroll
            for (int tj = 0; tj < 2; ++tj)
                acc[ti][tj] = __builtin_amdgcn_mfma_scale_f32_32x32x64_f8f6f4(
                    fra[sl][ti], frb[sl][tj], acc[ti][tj],
                    0, 0,                // cbsz=FP8(e4m3), blgp=FP8(e4m3)
                    0, 0x7f7f7f7f,       // scale_a opsel, E8M0 = 127 -> 1.0
                    0, 0x7f7f7f7f);      // scale_b
    }

    // 32x32 C/D layout: col = lane&31, row = (r&3) + 8*(r>>2) + 4*(lane>>5)
    const int hi  = lane >> 5, l31 = lane & 31;

    // row-sums: exp(2*c) summed over this block's 128 cols -> slot bj*2+wcol
    const int prow = bj * 2 + wcol;
    const int R0   = i0 + wrow * 64;
    #pragma unroll
    for (int ti = 0; ti < 2; ++ti) {
        #pragma unroll
        for (int r = 0; r < 16; ++r) {
            float ss = __expf(2.0f * acc[ti][0][r]) + __expf(2.0f * acc[ti][1][r]);
            #pragma unroll
            for (int off = 1; off < 32; off <<= 1) ss += __shfl_xor(ss, off);
            if (l31 == 0) {
                int rowg = R0 + ti * 32 + (r & 3) + 8 * (r >> 2) + 4 * hi;
                partial[(size_t)prow * N + rowg] = ss;
            }
        }
    }
    // col-sums (symmetry: = row-sums of skipped tile (bj,bi)) -> slot bi*2+wrow
    if (bi < bj) {
        const int pcol = bi * 2 + wrow;
        const int C0   = j0 + wcol * 64;
        #pragma unroll
        for (int tj = 0; tj < 2; ++tj) {
            float css = 0.f;
            #pragma unroll
            for (int ti = 0; ti < 2; ++ti)
                #pragma unroll
                for (int r = 0; r < 16; ++r) css += __expf(2.0f * acc[ti][tj][r]);
            css += __shfl_xor(css, 32);
            if (hi == 0) partial[(size_t)pcol * N + (C0 + tj * 32 + l31)] = css;
        }
    }
}

__global__ __launch_bounds__(256) void k_final(const float* __restrict__ partial,
                                               const float* __restrict__ pos,
                                               float* __restrict__ out) {
    int tid = threadIdx.x;
    int row = blockIdx.x * 64 + (tid >> 2);
    int sub = tid & 3;
    float S = 0.f;
    #pragma unroll
    for (int i = 0; i < 32; ++i) S += partial[(size_t)(sub + i * 4) * N + row];
    S += __shfl_xor(S, 1);
    S += __shfl_xor(S, 2);
    float val = (sub == 0) ? (logf(S) - 2.0f * pos[row]) : 0.0f;
    #pragma unroll
    for (int off = 4; off < 64; off <<= 1) val += __shfl_xor(val, off);
    if ((tid & 63) == 0) atomicAdd(out, val * (1.0f / (2.0f * N)));
}

extern "C" void kernel_launch(void* const* d_in, const int* in_sizes, int n_in,
                              void* d_out, int out_size, void* d_ws, size_t ws_size,
                              hipStream_t stream) {
    const float* emb = (const float*)d_in[0];
    const float* tgt = (const float*)d_in[1];
    unsigned char* neb = (unsigned char*)d_ws;                                   // 4 MB fp8 ne (MX layout v2)
    float* pos     = (float*)((char*)d_ws + (size_t)N * D);                      // 32 KB
    float* partial = (float*)((char*)d_ws + (size_t)N * D + (size_t)N * 4);      // 4 MB
    float* out = (float*)d_out;

    k_norm<<<N / 4, 256, 0, stream>>>(emb, tgt, neb, pos, out);
    k_gemm<<<NT * (NT + 1) / 2, 256, 0, stream>>>(neb, partial);
    k_final<<<N / 64, 256, 0, stream>>>(partial, pos, out);
}